// Round 13
// baseline (147.454 us; speedup 1.0000x reference)
//
#include <hip/hip_runtime.h>
#include <hip/hip_bf16.h>
#include <math.h>

#define NN 20000
#define EF 720000

typedef float  f4 __attribute__((ext_vector_type(4)));
typedef unsigned int u4 __attribute__((ext_vector_type(4)));

__device__ __forceinline__ void MFMA(f4& c, u4 a, u4 b) {
    asm("v_mfma_f32_16x16x32_bf16 %0, %1, %2, %0" : "+v"(c) : "v"(a), "v"(b));
}

__device__ __forceinline__ unsigned pk(float a, float b) {
    __hip_bfloat162 t = __halves2bfloat162(__float2bfloat16(a), __float2bfloat16(b));
    unsigned u; __builtin_memcpy(&u, &t, 4); return u;
}
__device__ __forceinline__ float bf2f(unsigned short u) {
    return __builtin_bit_cast(float, (unsigned)u << 16);
}
__device__ __forceinline__ f4 bf2f4(ushort4 u) {
    f4 r; r.x = bf2f(u.x); r.y = bf2f(u.y); r.z = bf2f(u.z); r.w = bf2f(u.w); return r;
}
__device__ __forceinline__ float dot4(f4 a, f4 b) {
    return a.x * b.x + a.y * b.y + a.z * b.z + a.w * b.w;
}

// ---------------------------------------------------------------- prep: bf16 weights + composed projections
__global__ __launch_bounds__(256) void k_prep(
    const float* __restrict__ mw1, const float* __restrict__ mb1,
    const float* __restrict__ mw2, const float* __restrict__ mw3,
    const float* __restrict__ hw1, const float* __restrict__ hw2, const float* __restrict__ hw3,
    const float* __restrict__ we, const float* __restrict__ wk, const float* __restrict__ bk,
    const float* __restrict__ wv, const float* __restrict__ bv,
    const float* __restrict__ wq, const float* __restrict__ bq,
    __hip_bfloat16* __restrict__ W1b, __hip_bfloat16* __restrict__ W2b, __hip_bfloat16* __restrict__ W3b,
    __hip_bfloat16* __restrict__ H1b, __hip_bfloat16* __restrict__ H2b, __hip_bfloat16* __restrict__ H3b,
    __hip_bfloat16* __restrict__ WcA, float* __restrict__ Mwe, float* __restrict__ Mk)
{
    int t = blockIdx.x * 256 + threadIdx.x;
    if (t < 2048) {  // W1b[ch][k], K=32: k<21 weights, k==21 bias, rest 0
        int ch = t >> 5, k = t & 31;
        float v = (k < 21) ? mw1[k * 64 + ch] : (k == 21 ? mb1[ch] : 0.f);
        W1b[t] = __float2bfloat16(v); return;
    }
    t -= 2048;
    if (t < 4096) { int ch = t >> 6, k = t & 63; W2b[t] = __float2bfloat16(mw2[k * 64 + ch]); return; }
    t -= 4096;
    if (t < 4096) { int ch = t >> 6, k = t & 63; W3b[t] = __float2bfloat16(mw3[k * 64 + ch]); return; }
    t -= 4096;
    if (t < 4096) { int ch = t >> 6, k = t & 63; H1b[t] = __float2bfloat16(hw1[k * 64 + ch]); return; }
    t -= 4096;
    if (t < 4096) { int ch = t >> 6, k = t & 63; H2b[t] = __float2bfloat16(hw2[k * 64 + ch]); return; }
    t -= 4096;
    if (t < 2048) {  // H3b padded to 32 rows
        int ch = t >> 6, k = t & 63;
        float v = (ch < 20) ? hw3[k * 20 + ch] : 0.f;
        H3b[t] = __float2bfloat16(v); return;
    }
    t -= 2048;
    if (t < 16384) {
        int h = t >> 13, rem = t & 8191;
        int ch = rem >> 7, k = rem & 127;
        int col = h * 64 + ch;
        float v;
        if (k < 64)        v = we[k * 128 + col];
        else if (k < 84)   v = wv[(k - 64) * 128 + col];
        else if (k == 84)  v = bv[col];
        else if (k < 96)   v = 0.f;
        else if (k < 116)  v = we[(64 + (k - 96)) * 128 + col];
        else               v = 0.f;
        WcA[t] = __float2bfloat16(v); return;
    }
    t -= 16384;
    if (t < 4032) {  // Mwe: 21 x 192 (96/head; a<84 real, rest 0)
        int j = t / 192, o = t % 192;
        int h = (o >= 96) ? 1 : 0, a = o - 96 * h;
        float acc = 0.f;
        if (a < 84) {
            for (int c = 0; c < 64; c++) {
                int hc = h * 64 + c;
                float wqv = (j < 20) ? wq[j * 128 + hc] : bq[hc];
                acc += wqv * we[a * 128 + hc];
            }
        }
        Mwe[t] = acc; return;
    }
    t -= 4032;
    if (t < 1344) {  // Mk: 21 x 64
        int j = t / 64, rem = t % 64;
        int h = rem >> 5, a = rem & 31;
        float acc = 0.f;
        if (a <= 20) {
            for (int c = 0; c < 64; c++) {
                int hc = h * 64 + c;
                float wqv = (j < 20) ? wq[j * 128 + hc] : bq[hc];
                float wkv = (a < 20) ? wk[a * 128 + hc] : bk[hc];
                acc += wqv * wkv;
            }
        }
        Mk[t] = acc; return;
    }
}

// ---------------------------------------------------------------- CSR via binary search
__global__ __launch_bounds__(256) void k_csr(
    const int* __restrict__ dst, const float* __restrict__ mask, int* __restrict__ row_off)
{
    int n = blockIdx.x * 256 + threadIdx.x;
    if (n > NN) return;
    int lo = 0, hi = EF;
    while (lo < hi) { int mid = (lo + hi) >> 1; if (mask[mid] > 0.5f) lo = mid + 1; else hi = mid; }
    int Ea = lo;
    lo = 0; hi = Ea;
    while (lo < hi) { int mid = (lo + hi) >> 1; if (dst[mid] < n) lo = mid + 1; else hi = mid; }
    row_off[n] = lo;
}

// ---------------------------------------------------------------- node features + composed projections + a00/a01
__global__ __launch_bounds__(256) void k_node(
    const float* __restrict__ angle, const float* __restrict__ mol, const float* __restrict__ gen,
    const int* __restrict__ row_off,
    const float* __restrict__ wskip, const float* __restrict__ bskip,
    const float* __restrict__ Mwe, const float* __restrict__ Mk,
    __hip_bfloat16* __restrict__ selffb,
    float* __restrict__ skipf, float* __restrict__ qwe, float* __restrict__ qkp,
    float* __restrict__ anode)
{
    int wid = threadIdx.x >> 6, lane = threadIdx.x & 63;
    int n = blockIdx.x * 4 + wid;

    float an = angle[n];
    float sv, cv; sincosf(an, &sv, &cv);
    float degf = (float)(row_off[n + 1] - row_off[n]);
    float sfa[21];
    sfa[0] = sv; sfa[1] = cv;
#pragma unroll
    for (int j = 0; j < 16; j++) sfa[2 + j] = mol[n * 16 + j];
    sfa[18] = gen[n];
    sfa[19] = degf;
    sfa[20] = 1.f;

    if (lane < 32) {
        float sval = (lane == 0) ? sv : (lane == 1) ? cv :
                     (lane < 18) ? mol[n * 16 + (lane - 2)] :
                     (lane == 18) ? gen[n] : (lane == 19) ? degf :
                     (lane == 20) ? 1.f : 0.f;
        selffb[n * 32 + lane] = __float2bfloat16(sval);
    }

    float sk = bskip[lane];
#pragma unroll
    for (int j = 0; j < 20; j++) sk += sfa[j] * wskip[j * 64 + lane];
    skipf[n * 64 + lane] = sk;

    float a00p = 0.f, a01p = 0.f;
#pragma unroll
    for (int r = 0; r < 3; r++) {
        int o = r * 64 + lane;
        float acc = 0.f;
#pragma unroll
        for (int j = 0; j < 21; j++) acc += sfa[j] * Mwe[j * 192 + o];
        qwe[n * 192 + o] = acc;
        if (r == 1 && lane < 20) a00p = sfa[lane] * acc;          // o = 64+j
        if (r == 2 && lane >= 32 && lane < 52) a01p = sfa[lane - 32] * acc;  // o = 160+j
    }
#pragma unroll
    for (int mk = 1; mk < 64; mk <<= 1) {
        a00p += __shfl_xor(a00p, mk, 64);
        a01p += __shfl_xor(a01p, mk, 64);
    }
    if (lane == 0) { anode[2 * n] = a00p; anode[2 * n + 1] = a01p; }

    {
        float acc = 0.f;
#pragma unroll
        for (int j = 0; j < 21; j++) acc += sfa[j] * Mk[j * 64 + lane];
        qkp[n * 64 + lane] = acc;
    }
}

// ---------------------------------------------------------------- edge MLP via MFMA (wave = 64 edges, 4 waves/block)
// Per-wave PRIVATE LDS slice; no __syncthreads (same-wave lgkmcnt ordering).
__device__ __forceinline__ void write_tiles(char* lds, int l, f4 (&acc)[4][4], const float* bias)
{
#pragma unroll
    for (int m = 0; m < 4; m++) {
        f4 bv;
        if (bias) bv = *(const f4*)(bias + m * 16 + ((l >> 4) << 2));
        else      { bv.x = 0.f; bv.y = 0.f; bv.z = 0.f; bv.w = 0.f; }
#pragma unroll
        for (int n = 0; n < 4; n++) {
            f4 v = acc[m][n];
            float v0 = fmaxf(v.x + bv.x, 0.f);
            float v1 = fmaxf(v.y + bv.y, 0.f);
            float v2 = fmaxf(v.z + bv.z, 0.f);
            float v3 = fmaxf(v.w + bv.w, 0.f);
            int e   = n * 16 + (l & 15);
            int ch0 = m * 16 + ((l >> 4) << 2);
            int byte = e * 128 + ((((ch0 >> 3) ^ (e & 7))) << 4) + (ch0 & 7) * 2;
            uint2 w; w.x = pk(v0, v1); w.y = pk(v2, v3);
            *(uint2*)(lds + byte) = w;
        }
    }
}

__global__ __launch_bounds__(256) void k_edge_mfma(
    const float* __restrict__ x, const float* __restrict__ angle, const float* __restrict__ mol,
    const int* __restrict__ src, const int* __restrict__ dst,
    const float* __restrict__ mask,
    const __hip_bfloat16* __restrict__ W1b, const __hip_bfloat16* __restrict__ W2b,
    const __hip_bfloat16* __restrict__ W3b,
    const float* __restrict__ mb2, const float* __restrict__ mb3,
    __hip_bfloat16* __restrict__ msg)
{
    __shared__ char lds_all[4][64 * 128];
    int wv = threadIdx.x >> 6, l = threadIdx.x & 63;
    char* lds = lds_all[wv];
    int e0 = (blockIdx.x * 4 + wv) * 64;
    if (e0 + 64 > EF) e0 = EF - 64;

    if (mask[e0] < 0.5f) return;

    int s = src[e0 + l], d = dst[e0 + l];
    float2 xs = ((const float2*)x)[s], xd = ((const float2*)x)[d];
    float dx = xs.x - xd.x, dy = xs.y - xd.y;
    float r = sqrtf(fmaxf(dx * dx + dy * dy, 1e-12f));
    float da = angle[s] - angle[d];
    float sv, cv; sincosf(da, &sv, &cv);
    const float4* m4 = (const float4*)mol;
    float4 sa = m4[s * 4 + 0], sb = m4[s * 4 + 1], sc = m4[s * 4 + 2], sd = m4[s * 4 + 3];
    float4 ta = m4[d * 4 + 0], tb = m4[d * 4 + 1], tc = m4[d * 4 + 2], td = m4[d * 4 + 3];
    float f[22];
    f[0] = dx; f[1] = dy; f[2] = r; f[3] = sv; f[4] = cv;
    f[5]  = sa.x - ta.x; f[6]  = sa.y - ta.y; f[7]  = sa.z - ta.z; f[8]  = sa.w - ta.w;
    f[9]  = sb.x - tb.x; f[10] = sb.y - tb.y; f[11] = sb.z - tb.z; f[12] = sb.w - tb.w;
    f[13] = sc.x - tc.x; f[14] = sc.y - tc.y; f[15] = sc.z - tc.z; f[16] = sc.w - tc.w;
    f[17] = sd.x - td.x; f[18] = sd.y - td.y; f[19] = sd.z - td.z; f[20] = sd.w - td.w;
    f[21] = 1.f;
    unsigned p[16];
#pragma unroll
    for (int j = 0; j < 11; j++) p[j] = pk(f[2 * j], f[2 * j + 1]);
#pragma unroll
    for (int j = 11; j < 16; j++) p[j] = 0u;
#pragma unroll
    for (int g = 0; g < 4; g++) {
        int byte = l * 64 + ((g ^ (l & 3)) << 4);
        u4 w; w.x = p[4 * g]; w.y = p[4 * g + 1]; w.z = p[4 * g + 2]; w.w = p[4 * g + 3];
        *(u4*)(lds + byte) = w;
    }

    u4 B1[4];
#pragma unroll
    for (int n = 0; n < 4; n++) {
        int e = n * 16 + (l & 15);
        int byte = e * 64 + ((((l >> 4) & 3) ^ (e & 3)) << 4);
        B1[n] = *(const u4*)(lds + byte);
    }

    f4 acc[4][4];
#pragma unroll
    for (int m = 0; m < 4; m++)
#pragma unroll
        for (int n = 0; n < 4; n++) { acc[m][n].x = 0.f; acc[m][n].y = 0.f; acc[m][n].z = 0.f; acc[m][n].w = 0.f; }

    const unsigned short* W1u = (const unsigned short*)W1b;
    const unsigned short* W2u = (const unsigned short*)W2b;
    const unsigned short* W3u = (const unsigned short*)W3b;
#pragma unroll
    for (int m = 0; m < 4; m++) {
        u4 w = *(const u4*)(W1u + (m * 16 + (l & 15)) * 32 + (l >> 4) * 8);
#pragma unroll
        for (int n = 0; n < 4; n++) MFMA(acc[m][n], w, B1[n]);
    }
    write_tiles(lds, l, acc, nullptr);

    u4 B2[4][2];
#pragma unroll
    for (int n = 0; n < 4; n++)
#pragma unroll
        for (int ks = 0; ks < 2; ks++) {
            int e = n * 16 + (l & 15);
            int g = ks * 4 + (l >> 4);
            B2[n][ks] = *(const u4*)(lds + e * 128 + ((g ^ (e & 7)) << 4));
        }
#pragma unroll
    for (int m = 0; m < 4; m++)
#pragma unroll
        for (int n = 0; n < 4; n++) { acc[m][n].x = 0.f; acc[m][n].y = 0.f; acc[m][n].z = 0.f; acc[m][n].w = 0.f; }
#pragma unroll
    for (int m = 0; m < 4; m++)
#pragma unroll
        for (int ks = 0; ks < 2; ks++) {
            u4 w = *(const u4*)(W2u + (m * 16 + (l & 15)) * 64 + ks * 32 + (l >> 4) * 8);
#pragma unroll
            for (int n = 0; n < 4; n++) MFMA(acc[m][n], w, B2[n][ks]);
        }
    write_tiles(lds, l, acc, mb2);

#pragma unroll
    for (int n = 0; n < 4; n++)
#pragma unroll
        for (int ks = 0; ks < 2; ks++) {
            int e = n * 16 + (l & 15);
            int g = ks * 4 + (l >> 4);
            B2[n][ks] = *(const u4*)(lds + e * 128 + ((g ^ (e & 7)) << 4));
        }
#pragma unroll
    for (int m = 0; m < 4; m++)
#pragma unroll
        for (int n = 0; n < 4; n++) { acc[m][n].x = 0.f; acc[m][n].y = 0.f; acc[m][n].z = 0.f; acc[m][n].w = 0.f; }
#pragma unroll
    for (int m = 0; m < 4; m++)
#pragma unroll
        for (int ks = 0; ks < 2; ks++) {
            u4 w = *(const u4*)(W3u + (m * 16 + (l & 15)) * 64 + ks * 32 + (l >> 4) * 8);
#pragma unroll
            for (int n = 0; n < 4; n++) MFMA(acc[m][n], w, B2[n][ks]);
        }

    // stage-3 epilogue: bias+relu+pack, store DIRECTLY from fragments to msg
#pragma unroll
    for (int m = 0; m < 4; m++) {
        f4 bv = *(const f4*)(mb3 + m * 16 + ((l >> 4) << 2));
#pragma unroll
        for (int n = 0; n < 4; n++) {
            f4 v = acc[m][n];
            float v0 = fmaxf(v.x + bv.x, 0.f);
            float v1 = fmaxf(v.y + bv.y, 0.f);
            float v2 = fmaxf(v.z + bv.z, 0.f);
            float v3 = fmaxf(v.w + bv.w, 0.f);
            int e   = n * 16 + (l & 15);
            int ch0 = m * 16 + ((l >> 4) << 2);
            uint2 w; w.x = pk(v0, v1); w.y = pk(v2, v3);
            *(uint2*)((unsigned short*)msg + (size_t)(e0 + e) * 64 + ch0) = w;
        }
    }
}

// ---------------------------------------------------------------- attention aggregate (8 edge-groups of 8 lanes)
// lane (g=lane>>3, c8=lane&7): owns msg channels 8*c8..+7 and sf/qk slots 4*c8..4*c8+3
// (slots 21..31 are structurally zero, so the 32-slot partition equals the 21-term sums).
// agg[n][256] bf16 per head h (base h*128): [0..63]=Wm_h, [64..95]=Ws_h (slot 84? no: slot 64+20 = S_h),
// [96..127]=S_h*sf. invp[n][2] = 1/(S_h+1e-16).
__global__ __launch_bounds__(256) void k_attn(
    const int* __restrict__ row_off, const int* __restrict__ src,
    const __hip_bfloat16* __restrict__ msg,
    const __hip_bfloat16* __restrict__ selffb, const float* __restrict__ qkp,
    const float* __restrict__ qwe, const float* __restrict__ anode,
    __hip_bfloat16* __restrict__ agg, float* __restrict__ invp)
{
    int tid = threadIdx.x, wid = tid >> 6, lane = tid & 63;
    int g = lane >> 3, c8 = lane & 7;
    int n = blockIdx.x * 4 + wid;

    const float* qrow = qwe + (size_t)n * 192;
    f4 qmA0 = *(const f4*)(qrow + 8 * c8);
    f4 qmA1 = *(const f4*)(qrow + 8 * c8 + 4);
    f4 qmB0 = *(const f4*)(qrow + 96 + 8 * c8);
    f4 qmB1 = *(const f4*)(qrow + 96 + 8 * c8 + 4);
    f4 qk0 = *(const f4*)(qkp + n * 64 + 4 * c8);        // slots 4c8..+3 (>=21 are 0)
    f4 qk1 = *(const f4*)(qkp + n * 64 + 32 + 4 * c8);
    float2 av = *(const float2*)(anode + 2 * n);
    float a00 = av.x, a01 = av.y;

    const unsigned short* msgu = (const unsigned short*)msg;
    const unsigned short* sfu  = (const unsigned short*)selffb;
    f4 sfd = bf2f4(*(const ushort4*)(sfu + (size_t)n * 32 + 4 * c8));  // dst self-feat slice

    int r0 = row_off[n], r1 = row_off[n + 1];
    int nit = (r1 - r0 + 7) >> 3;

    f4 WmA0 = {0,0,0,0}, WmA1 = {0,0,0,0}, WmB0 = {0,0,0,0}, WmB1 = {0,0,0,0};
    f4 Ws0 = {0,0,0,0}, Ws1 = {0,0,0,0};
    float S0 = 0.f, S1 = 0.f;

#pragma unroll 2
    for (int it = 0; it < nit; it++) {
        int e = r0 + it * 8 + g;
        bool ok = (e < r1);
        int ec = ok ? e : r0;
        int s = src[ec];
        f4 sfv = bf2f4(*(const ushort4*)(sfu + (size_t)s * 32 + 4 * c8));
        u4 mr = *(const u4*)(msgu + (size_t)ec * 64 + 8 * c8);
        float c0 = __builtin_bit_cast(float, mr.x << 16);
        float c1 = __builtin_bit_cast(float, mr.x & 0xffff0000u);
        float c2 = __builtin_bit_cast(float, mr.y << 16);
        float c3 = __builtin_bit_cast(float, mr.y & 0xffff0000u);
        float c4 = __builtin_bit_cast(float, mr.z << 16);
        float c5 = __builtin_bit_cast(float, mr.z & 0xffff0000u);
        float c6 = __builtin_bit_cast(float, mr.w << 16);
        float c7 = __builtin_bit_cast(float, mr.w & 0xffff0000u);

        float t0 = qmA0.x * c0 + qmA0.y * c1 + qmA0.z * c2 + qmA0.w * c3
                 + qmA1.x * c4 + qmA1.y * c5 + qmA1.z * c6 + qmA1.w * c7
                 + dot4(sfv, qk0);
        float t1 = qmB0.x * c0 + qmB0.y * c1 + qmB0.z * c2 + qmB0.w * c3
                 + qmB1.x * c4 + qmB1.y * c5 + qmB1.z * c6 + qmB1.w * c7
                 + dot4(sfv, qk1);
#pragma unroll
        for (int mk = 1; mk < 8; mk <<= 1) {
            t0 += __shfl_xor(t0, mk, 64);
            t1 += __shfl_xor(t1, mk, 64);
        }
        float w0 = ok ? __expf((t0 + a00) * 0.125f) : 0.f;
        float w1 = ok ? __expf((t1 + a01) * 0.125f) : 0.f;
        S0 += w0; S1 += w1;
        WmA0.x += w0 * c0; WmA0.y += w0 * c1; WmA0.z += w0 * c2; WmA0.w += w0 * c3;
        WmA1.x += w0 * c4; WmA1.y += w0 * c5; WmA1.z += w0 * c6; WmA1.w += w0 * c7;
        WmB0.x += w1 * c0; WmB0.y += w1 * c1; WmB0.z += w1 * c2; WmB0.w += w1 * c3;
        WmB1.x += w1 * c4; WmB1.y += w1 * c5; WmB1.z += w1 * c6; WmB1.w += w1 * c7;
        Ws0.x += w0 * sfv.x; Ws0.y += w0 * sfv.y; Ws0.z += w0 * sfv.z; Ws0.w += w0 * sfv.w;
        Ws1.x += w1 * sfv.x; Ws1.y += w1 * sfv.y; Ws1.z += w1 * sfv.z; Ws1.w += w1 * sfv.w;
    }

    // cross-group butterfly (xor 8,16,32): every lane ends with full-node totals
#pragma unroll
    for (int mk = 8; mk <= 32; mk <<= 1) {
        WmA0.x += __shfl_xor(WmA0.x, mk, 64); WmA0.y += __shfl_xor(WmA0.y, mk, 64);
        WmA0.z += __shfl_xor(WmA0.z, mk, 64); WmA0.w += __shfl_xor(WmA0.w, mk, 64);
        WmA1.x += __shfl_xor(WmA1.x, mk, 64); WmA1.y += __shfl_xor(WmA1.y, mk, 64);
        WmA1.z += __shfl_xor(WmA1.z, mk, 64); WmA1.w += __shfl_xor(WmA1.w, mk, 64);
        WmB0.x += __shfl_xor(WmB0.x, mk, 64); WmB0.y += __shfl_xor(WmB0.y, mk, 64);
        WmB0.z += __shfl_xor(WmB0.z, mk, 64); WmB0.w += __shfl_xor(WmB0.w, mk, 64);
        WmB1.x += __shfl_xor(WmB1.x, mk, 64); WmB1.y += __shfl_xor(WmB1.y, mk, 64);
        WmB1.z += __shfl_xor(WmB1.z, mk, 64); WmB1.w += __shfl_xor(WmB1.w, mk, 64);
        Ws0.x += __shfl_xor(Ws0.x, mk, 64); Ws0.y += __shfl_xor(Ws0.y, mk, 64);
        Ws0.z += __shfl_xor(Ws0.z, mk, 64); Ws0.w += __shfl_xor(Ws0.w, mk, 64);
        Ws1.x += __shfl_xor(Ws1.x, mk, 64); Ws1.y += __shfl_xor(Ws1.y, mk, 64);
        Ws1.z += __shfl_xor(Ws1.z, mk, 64); Ws1.w += __shfl_xor(Ws1.w, mk, 64);
        S0 += __shfl_xor(S0, mk, 64); S1 += __shfl_xor(S1, mk, 64);
    }

    unsigned short* arow = (unsigned short*)agg + (size_t)n * 256;
    if (g == 0) {          // head0 Wm
        u4 w; w.x = pk(WmA0.x, WmA0.y); w.y = pk(WmA0.z, WmA0.w);
        w.z = pk(WmA1.x, WmA1.y); w.w = pk(WmA1.z, WmA1.w);
        *(u4*)(arow + 8 * c8) = w;
    } else if (g == 1) {   // head1 Wm
        u4 w; w.x = pk(WmB0.x, WmB0.y); w.y = pk(WmB0.z, WmB0.w);
        w.z = pk(WmB1.x, WmB1.y); w.w = pk(WmB1.z, WmB1.w);
        *(u4*)(arow + 128 + 8 * c8) = w;
    } else if (g == 2) {   // head0 Ws slots 4c8..+3 (slot 20 = S0 via sfb[20]=1)
        uint2 w; w.x = pk(Ws0.x, Ws0.y); w.y = pk(Ws0.z, Ws0.w);
        *(uint2*)(arow + 64 + 4 * c8) = w;
    } else if (g == 3) {   // head1 Ws
        uint2 w; w.x = pk(Ws1.x, Ws1.y); w.y = pk(Ws1.z, Ws1.w);
        *(uint2*)(arow + 128 + 64 + 4 * c8) = w;
    } else if (g == 4) {   // head0 S*sf
        uint2 w; w.x = pk(S0 * sfd.x, S0 * sfd.y); w.y = pk(S0 * sfd.z, S0 * sfd.w);
        *(uint2*)(arow + 96 + 4 * c8) = w;
    } else if (g == 5) {   // head1 S*sf
        uint2 w; w.x = pk(S1 * sfd.x, S1 * sfd.y); w.y = pk(S1 * sfd.z, S1 * sfd.w);
        *(uint2*)(arow + 128 + 96 + 4 * c8) = w;
    } else if (g == 6 && c8 == 0) {
        invp[2 * n]     = 1.f / (S0 + 1e-16f);
        invp[2 * n + 1] = 1.f / (S1 + 1e-16f);
    }
}

// ---------------------------------------------------------------- fused attn-epilogue + final MLP (1 wave = 64 nodes)
__global__ __launch_bounds__(64) void k_final2(
    const __hip_bfloat16* __restrict__ agg, const float* __restrict__ invp,
    const float* __restrict__ skipf, const __hip_bfloat16* __restrict__ WcA,
    const __hip_bfloat16* __restrict__ H1b, const __hip_bfloat16* __restrict__ H2b,
    const __hip_bfloat16* __restrict__ H3b,
    const float* __restrict__ hb1, const float* __restrict__ hb2, const float* __restrict__ hb3,
    float* __restrict__ out)
{
    __shared__ char lds[64 * 128];
    int l = threadIdx.x;
    int n0 = blockIdx.x * 64;

    const unsigned short* aggU = (const unsigned short*)agg;
    const unsigned short* WcU = (const unsigned short*)WcA;
    const unsigned short* H1u = (const unsigned short*)H1b;
    const unsigned short* H2u = (const unsigned short*)H2b;
    const unsigned short* H3u = (const unsigned short*)H3b;

    int nodes[4];
    float inv0[4], inv1[4];
#pragma unroll
    for (int n4 = 0; n4 < 4; n4++) {
        int node = n0 + n4 * 16 + (l & 15); if (node >= NN) node = NN - 1;
        nodes[n4] = node;
        float2 iv = *(const float2*)(invp + 2 * node);
        inv0[n4] = iv.x; inv1[n4] = iv.y;
    }

    f4 osum[4][4];
#pragma unroll
    for (int m = 0; m < 4; m++)
#pragma unroll
        for (int n4 = 0; n4 < 4; n4++) { osum[m][n4].x = 0.f; osum[m][n4].y = 0.f; osum[m][n4].z = 0.f; osum[m][n4].w = 0.f; }

#pragma unroll
    for (int h = 0; h < 2; h++) {
        f4 acc[4][4];
#pragma unroll
        for (int m = 0; m < 4; m++)
#pragma unroll
            for (int n4 = 0; n4 < 4; n4++) { acc[m][n4].x = 0.f; acc[m][n4].y = 0.f; acc[m][n4].z = 0.f; acc[m][n4].w = 0.f; }
#pragma unroll
        for (int ks = 0; ks < 4; ks++) {
            u4 A[4];
#pragma unroll
            for (int m = 0; m < 4; m++)
                A[m] = *(const u4*)(WcU + h * 8192 + (m * 16 + (l & 15)) * 128 + ks * 32 + (l >> 4) * 8);
#pragma unroll
            for (int n4 = 0; n4 < 4; n4++) {
                u4 B = *(const u4*)(aggU + (size_t)nodes[n4] * 256 + h * 128 + ks * 32 + (l >> 4) * 8);
#pragma unroll
                for (int m = 0; m < 4; m++) MFMA(acc[m][n4], A[m], B);
            }
        }
        const float* iv = h ? inv1 : inv0;
#pragma unroll
        for (int m = 0; m < 4; m++)
#pragma unroll
            for (int n4 = 0; n4 < 4; n4++) {
                float s = 0.5f * iv[n4];
                osum[m][n4].x += s * acc[m][n4].x; osum[m][n4].y += s * acc[m][n4].y;
                osum[m][n4].z += s * acc[m][n4].z; osum[m][n4].w += s * acc[m][n4].w;
            }
    }

#pragma unroll
    for (int m = 0; m < 4; m++) {
#pragma unroll
        for (int n4 = 0; n4 < 4; n4++) {
            int ch0 = m * 16 + ((l >> 4) << 2);
            float4 sk = *(const float4*)(skipf + (size_t)nodes[n4] * 64 + ch0);
            f4 v = osum[m][n4];
            float v0 = v.x + sk.x, v1 = v.y + sk.y, v2 = v.z + sk.z, v3 = v.w + sk.w;
            int e = n4 * 16 + (l & 15);
            int byte = e * 128 + ((((ch0 >> 3) ^ (e & 7))) << 4) + (ch0 & 7) * 2;
            uint2 w; w.x = pk(v0, v1); w.y = pk(v2, v3);
            *(uint2*)(lds + byte) = w;
        }
    }
    __syncthreads();

    u4 B[4][2];
    f4 acc[4][4];

    // ---- stage 1
#pragma unroll
    for (int n = 0; n < 4; n++)
#pragma unroll
        for (int ks = 0; ks < 2; ks++) {
            int e = n * 16 + (l & 15);
            int g = ks * 4 + (l >> 4);
            B[n][ks] = *(const u4*)(lds + e * 128 + ((g ^ (e & 7)) << 4));
        }
    __syncthreads();
#pragma unroll
    for (int m = 0; m < 4; m++)
#pragma unroll
        for (int n = 0; n < 4; n++) { acc[m][n].x = 0.f; acc[m][n].y = 0.f; acc[m][n].z = 0.f; acc[m][n].w = 0.f; }
#pragma unroll
    for (int m = 0; m < 4; m++)
#pragma unroll
        for (int ks = 0; ks < 2; ks++) {
            u4 w = *(const u4*)(H1u + (m * 16 + (l & 15)) * 64 + ks * 32 + (l >> 4) * 8);
#pragma unroll
            for (int n = 0; n < 4; n++) MFMA(acc[m][n], w, B[n][ks]);
        }
    write_tiles(lds, l, acc, hb1);
    __syncthreads();

    // ---- stage 2
#pragma unroll
    for (int n = 0; n < 4; n++)
#pragma unroll
        for (int ks = 0; ks < 2; ks++) {
            int e = n * 16 + (l & 15);
            int g = ks * 4 + (l >> 4);
            B[n][ks] = *(const u4*)(lds + e * 128 + ((g ^ (e & 7)) << 4));
        }
    __syncthreads();
#pragma unroll
    for (int m = 0; m < 4; m++)
#pragma unroll
        for (int n = 0; n < 4; n++) { acc[m][n].x = 0.f; acc[m][n].y = 0.f; acc[m][n].z = 0.f; acc[m][n].w = 0.f; }
#pragma unroll
    for (int m = 0; m < 4; m++)
#pragma unroll
        for (int ks = 0; ks < 2; ks++) {
            u4 w = *(const u4*)(H2u + (m * 16 + (l & 15)) * 64 + ks * 32 + (l >> 4) * 8);
#pragma unroll
            for (int n = 0; n < 4; n++) MFMA(acc[m][n], w, B[n][ks]);
        }
    write_tiles(lds, l, acc, hb2);
    __syncthreads();

    // ---- stage 3: 64 -> 20
#pragma unroll
    for (int n = 0; n < 4; n++)
#pragma unroll
        for (int ks = 0; ks < 2; ks++) {
            int e = n * 16 + (l & 15);
            int g = ks * 4 + (l >> 4);
            B[n][ks] = *(const u4*)(lds + e * 128 + ((g ^ (e & 7)) << 4));
        }

    f4 acc3[2][4];
#pragma unroll
    for (int m = 0; m < 2; m++)
#pragma unroll
        for (int n = 0; n < 4; n++) { acc3[m][n].x = 0.f; acc3[m][n].y = 0.f; acc3[m][n].z = 0.f; acc3[m][n].w = 0.f; }
#pragma unroll
    for (int m = 0; m < 2; m++)
#pragma unroll
        for (int ks = 0; ks < 2; ks++) {
            u4 w = *(const u4*)(H3u + (m * 16 + (l & 15)) * 64 + ks * 32 + (l >> 4) * 8);
#pragma unroll
            for (int n = 0; n < 4; n++) MFMA(acc3[m][n], w, B[n][ks]);
        }

#pragma unroll
    for (int m = 0; m < 2; m++) {
#pragma unroll
        for (int j = 0; j < 4; j++) {
            int ch = m * 16 + (l >> 4) * 4 + j;
            if (ch < 20) {
                float b = hb3[ch];
#pragma unroll
                for (int nt = 0; nt < 4; nt++) {
                    int node = n0 + nt * 16 + (l & 15);
                    if (node < NN) {
                        float v = acc3[m][nt][j] + b;
                        if (ch < 2)       out[node * 2 + ch] = v;
                        else if (ch == 2) out[2 * NN + node] = v;
                        else if (ch < 19) out[3 * NN + node * 16 + (ch - 3)] = v;
                        else              out[19 * NN + node] = v;
                    }
                }
            }
        }
    }
}

// ---------------------------------------------------------------- launch
extern "C" void kernel_launch(void* const* d_in, const int* in_sizes, int n_in,
                              void* d_out, int out_size, void* d_ws, size_t ws_size,
                              hipStream_t stream)
{
    const float* x      = (const float*)d_in[0];
    const float* angle  = (const float*)d_in[1];
    const float* mol    = (const float*)d_in[2];
    const float* gen    = (const float*)d_in[3];
    const int*   src    = (const int*)d_in[4];
    const int*   dst    = (const int*)d_in[5];
    const float* mask   = (const float*)d_in[6];
    const float* mw1    = (const float*)d_in[7];
    const float* mb1    = (const float*)d_in[8];
    const float* mw2    = (const float*)d_in[9];
    const float* mb2    = (const float*)d_in[10];
    const float* mw3    = (const float*)d_in[11];
    const float* mb3    = (const float*)d_in[12];
    const float* wq     = (const float*)d_in[13];
    const float* bq     = (const float*)d_in[14];
    const float* wk     = (const float*)d_in[15];
    const float* bk     = (const float*)d_in[16];
    const float* wv     = (const float*)d_in[17];
    const float* bv     = (const float*)d_in[18];
    const float* we     = (const float*)d_in[19];
    const float* wskip  = (const float*)d_in[20];
    const float* bskip  = (const float*)d_in[21];
    const float* hw1    = (const float*)d_in[22];
    const float* hb1    = (const float*)d_in[23];
    const float* hw2    = (const float*)d_in[24];
    const float* hb2    = (const float*)d_in[25];
    const float* hw3    = (const float*)d_in[26];
    const float* hb3    = (const float*)d_in[27];
    float* out = (float*)d_out;

    char* p = (char*)d_ws;
    auto alloc = [&](size_t bytes) -> void* {
        void* r = (void*)p;
        p += (bytes + 255) & ~(size_t)255;
        return r;
    };
    int*   row_off = (int*)alloc((NN + 1) * 4);
    __hip_bfloat16* selffb = (__hip_bfloat16*)alloc((size_t)NN * 32 * 2);
    float* qkp     = (float*)alloc((size_t)NN * 64 * 4);
    float* skipf   = (float*)alloc((size_t)NN * 64 * 4);
    float* qwe     = (float*)alloc((size_t)NN * 192 * 4);
    float* anode   = (float*)alloc((size_t)NN * 2 * 4);
    __hip_bfloat16* agg = (__hip_bfloat16*)alloc((size_t)NN * 256 * 2);
    float* invp    = (float*)alloc((size_t)NN * 2 * 4);
    __hip_bfloat16* W1b = (__hip_bfloat16*)alloc(2048 * 2);
    __hip_bfloat16* W2b = (__hip_bfloat16*)alloc(4096 * 2);
    __hip_bfloat16* W3b = (__hip_bfloat16*)alloc(4096 * 2);
    __hip_bfloat16* H1b = (__hip_bfloat16*)alloc(4096 * 2);
    __hip_bfloat16* H2b = (__hip_bfloat16*)alloc(4096 * 2);
    __hip_bfloat16* H3b = (__hip_bfloat16*)alloc(2048 * 2);
    __hip_bfloat16* WcA = (__hip_bfloat16*)alloc(16384 * 2);
    float* Mwe     = (float*)alloc(4032 * 4);
    float* Mk      = (float*)alloc(1344 * 4);
    __hip_bfloat16* msg = (__hip_bfloat16*)alloc((size_t)EF * 64 * 2);

    k_prep<<<165, 256, 0, stream>>>(mw1, mb1, mw2, mw3, hw1, hw2, hw3, we, wk, bk, wv, bv,
                                    wq, bq, W1b, W2b, W3b, H1b, H2b, H3b, WcA, Mwe, Mk);
    k_csr<<<(NN + 256) / 256, 256, 0, stream>>>(dst, mask, row_off);
    k_node<<<NN / 4, 256, 0, stream>>>(angle, mol, gen, row_off,
                                       wskip, bskip, Mwe, Mk,
                                       selffb, skipf, qwe, qkp, anode);
    k_edge_mfma<<<(EF / 64 + 3) / 4, 256, 0, stream>>>(x, angle, mol, src, dst, mask,
                                                       W1b, W2b, W3b, mb2, mb3, msg);
    k_attn<<<NN / 4, 256, 0, stream>>>(row_off, src, msg, selffb, qkp,
                                       qwe, anode, agg, invp);
    k_final2<<<(NN + 63) / 64, 64, 0, stream>>>(agg, invp, skipf, WcA,
                                                H1b, H2b, H3b, hb1, hb2, hb3, out);
}

// Round 14
// 133.707 us; speedup vs baseline: 1.1028x; 1.1028x over previous
//
#include <hip/hip_runtime.h>
#include <hip/hip_bf16.h>
#include <math.h>

#define NN 20000
#define EF 720000
#define EB 2813  // edge blocks: ceil((EF/64)/4)

typedef float  f4 __attribute__((ext_vector_type(4)));
typedef unsigned int u4 __attribute__((ext_vector_type(4)));

__device__ __forceinline__ void MFMA(f4& c, u4 a, u4 b) {
    asm("v_mfma_f32_16x16x32_bf16 %0, %1, %2, %0" : "+v"(c) : "v"(a), "v"(b));
}

__device__ __forceinline__ unsigned pk(float a, float b) {
    __hip_bfloat162 t = __halves2bfloat162(__float2bfloat16(a), __float2bfloat16(b));
    unsigned u; __builtin_memcpy(&u, &t, 4); return u;
}
__device__ __forceinline__ float bf2f(unsigned short u) {
    return __builtin_bit_cast(float, (unsigned)u << 16);
}
__device__ __forceinline__ f4 bf2f4(ushort4 u) {
    f4 r; r.x = bf2f(u.x); r.y = bf2f(u.y); r.z = bf2f(u.z); r.w = bf2f(u.w); return r;
}
__device__ __forceinline__ float dot4(f4 a, f4 b) {
    return a.x * b.x + a.y * b.y + a.z * b.z + a.w * b.w;
}

// ---------------------------------------------------------------- prep: bf16 weights + composed projections
__global__ __launch_bounds__(256) void k_prep(
    const float* __restrict__ mw1, const float* __restrict__ mb1,
    const float* __restrict__ mw2, const float* __restrict__ mw3,
    const float* __restrict__ hw1, const float* __restrict__ hw2, const float* __restrict__ hw3,
    const float* __restrict__ we, const float* __restrict__ wk, const float* __restrict__ bk,
    const float* __restrict__ wv, const float* __restrict__ bv,
    const float* __restrict__ wq, const float* __restrict__ bq,
    __hip_bfloat16* __restrict__ W1b, __hip_bfloat16* __restrict__ W2b, __hip_bfloat16* __restrict__ W3b,
    __hip_bfloat16* __restrict__ H1b, __hip_bfloat16* __restrict__ H2b, __hip_bfloat16* __restrict__ H3b,
    __hip_bfloat16* __restrict__ WcA, float* __restrict__ Mwe, float* __restrict__ Mk)
{
    int t = blockIdx.x * 256 + threadIdx.x;
    if (t < 2048) {  // W1b[ch][k], K=32: k<21 weights, k==21 bias, rest 0
        int ch = t >> 5, k = t & 31;
        float v = (k < 21) ? mw1[k * 64 + ch] : (k == 21 ? mb1[ch] : 0.f);
        W1b[t] = __float2bfloat16(v); return;
    }
    t -= 2048;
    if (t < 4096) { int ch = t >> 6, k = t & 63; W2b[t] = __float2bfloat16(mw2[k * 64 + ch]); return; }
    t -= 4096;
    if (t < 4096) { int ch = t >> 6, k = t & 63; W3b[t] = __float2bfloat16(mw3[k * 64 + ch]); return; }
    t -= 4096;
    if (t < 4096) { int ch = t >> 6, k = t & 63; H1b[t] = __float2bfloat16(hw1[k * 64 + ch]); return; }
    t -= 4096;
    if (t < 4096) { int ch = t >> 6, k = t & 63; H2b[t] = __float2bfloat16(hw2[k * 64 + ch]); return; }
    t -= 4096;
    if (t < 2048) {  // H3b padded to 32 rows
        int ch = t >> 6, k = t & 63;
        float v = (ch < 20) ? hw3[k * 20 + ch] : 0.f;
        H3b[t] = __float2bfloat16(v); return;
    }
    t -= 2048;
    if (t < 16384) {
        int h = t >> 13, rem = t & 8191;
        int ch = rem >> 7, k = rem & 127;
        int col = h * 64 + ch;
        float v;
        if (k < 64)        v = we[k * 128 + col];
        else if (k < 84)   v = wv[(k - 64) * 128 + col];
        else if (k == 84)  v = bv[col];
        else if (k < 96)   v = 0.f;
        else if (k < 116)  v = we[(64 + (k - 96)) * 128 + col];
        else               v = 0.f;
        WcA[t] = __float2bfloat16(v); return;
    }
    t -= 16384;
    if (t < 4032) {  // Mwe: 21 x 192 (96/head; a<84 real, rest 0)
        int j = t / 192, o = t % 192;
        int h = (o >= 96) ? 1 : 0, a = o - 96 * h;
        float acc = 0.f;
        if (a < 84) {
            for (int c = 0; c < 64; c++) {
                int hc = h * 64 + c;
                float wqv = (j < 20) ? wq[j * 128 + hc] : bq[hc];
                acc += wqv * we[a * 128 + hc];
            }
        }
        Mwe[t] = acc; return;
    }
    t -= 4032;
    if (t < 1344) {  // Mk: 21 x 64
        int j = t / 64, rem = t % 64;
        int h = rem >> 5, a = rem & 31;
        float acc = 0.f;
        if (a <= 20) {
            for (int c = 0; c < 64; c++) {
                int hc = h * 64 + c;
                float wqv = (j < 20) ? wq[j * 128 + hc] : bq[hc];
                float wkv = (a < 20) ? wk[a * 128 + hc] : bk[hc];
                acc += wqv * wkv;
            }
        }
        Mk[t] = acc; return;
    }
}

// ---------------------------------------------------------------- CSR via binary search
__global__ __launch_bounds__(256) void k_csr(
    const int* __restrict__ dst, const float* __restrict__ mask, int* __restrict__ row_off)
{
    int n = blockIdx.x * 256 + threadIdx.x;
    if (n > NN) return;
    int lo = 0, hi = EF;
    while (lo < hi) { int mid = (lo + hi) >> 1; if (mask[mid] > 0.5f) lo = mid + 1; else hi = mid; }
    int Ea = lo;
    lo = 0; hi = Ea;
    while (lo < hi) { int mid = (lo + hi) >> 1; if (dst[mid] < n) lo = mid + 1; else hi = mid; }
    row_off[n] = lo;
}

// ---------------------------------------------------------------- fused edge-MLP (blocks < EB) + node projections (blocks >= EB)
// Edge path: wave = 64 edges, per-wave PRIVATE LDS slice, no __syncthreads
// (same-wave LDS write->read ordering via compiler lgkmcnt). Node path: wave = 1 node.
__device__ __forceinline__ void write_tiles(char* lds, int l, f4 (&acc)[4][4], const float* bias)
{
#pragma unroll
    for (int m = 0; m < 4; m++) {
        f4 bv;
        if (bias) bv = *(const f4*)(bias + m * 16 + ((l >> 4) << 2));
        else      { bv.x = 0.f; bv.y = 0.f; bv.z = 0.f; bv.w = 0.f; }
#pragma unroll
        for (int n = 0; n < 4; n++) {
            f4 v = acc[m][n];
            float v0 = fmaxf(v.x + bv.x, 0.f);
            float v1 = fmaxf(v.y + bv.y, 0.f);
            float v2 = fmaxf(v.z + bv.z, 0.f);
            float v3 = fmaxf(v.w + bv.w, 0.f);
            int e   = n * 16 + (l & 15);
            int ch0 = m * 16 + ((l >> 4) << 2);
            int byte = e * 128 + ((((ch0 >> 3) ^ (e & 7))) << 4) + (ch0 & 7) * 2;
            uint2 w; w.x = pk(v0, v1); w.y = pk(v2, v3);
            *(uint2*)(lds + byte) = w;
        }
    }
}

__global__ __launch_bounds__(256) void k_edge_node(
    const float* __restrict__ x, const float* __restrict__ angle, const float* __restrict__ mol,
    const float* __restrict__ gen,
    const int* __restrict__ src, const int* __restrict__ dst,
    const float* __restrict__ mask, const int* __restrict__ row_off,
    const __hip_bfloat16* __restrict__ W1b, const __hip_bfloat16* __restrict__ W2b,
    const __hip_bfloat16* __restrict__ W3b,
    const float* __restrict__ mb2, const float* __restrict__ mb3,
    const float* __restrict__ wskip, const float* __restrict__ bskip,
    const float* __restrict__ Mwe, const float* __restrict__ Mk,
    __hip_bfloat16* __restrict__ msg,
    __hip_bfloat16* __restrict__ selffb, float* __restrict__ skipf,
    float* __restrict__ qwe, float* __restrict__ qkp, float* __restrict__ anode)
{
    __shared__ char lds_all[4][64 * 128];
    int wv = threadIdx.x >> 6, l = threadIdx.x & 63;

    if ((int)blockIdx.x >= EB) {
        // ---------------- node path: wave = 1 node
        int n = ((int)blockIdx.x - EB) * 4 + wv;

        float an = angle[n];
        float sv, cv; sincosf(an, &sv, &cv);
        float degf = (float)(row_off[n + 1] - row_off[n]);
        float sfa[21];
        sfa[0] = sv; sfa[1] = cv;
#pragma unroll
        for (int j = 0; j < 16; j++) sfa[2 + j] = mol[n * 16 + j];
        sfa[18] = gen[n];
        sfa[19] = degf;
        sfa[20] = 1.f;

        if (l < 32) {
            float sval = (l == 0) ? sv : (l == 1) ? cv :
                         (l < 18) ? mol[n * 16 + (l - 2)] :
                         (l == 18) ? gen[n] : (l == 19) ? degf :
                         (l == 20) ? 1.f : 0.f;
            selffb[n * 32 + l] = __float2bfloat16(sval);
        }

        float sk = bskip[l];
#pragma unroll
        for (int j = 0; j < 20; j++) sk += sfa[j] * wskip[j * 64 + l];
        skipf[n * 64 + l] = sk;

        float a00p = 0.f, a01p = 0.f;
#pragma unroll
        for (int r = 0; r < 3; r++) {
            int o = r * 64 + l;
            float acc = 0.f;
#pragma unroll
            for (int j = 0; j < 21; j++) acc += sfa[j] * Mwe[j * 192 + o];
            qwe[n * 192 + o] = acc;
            if (r == 1 && l < 20) a00p = sfa[l] * acc;
            if (r == 2 && l >= 32 && l < 52) a01p = sfa[l - 32] * acc;
        }
#pragma unroll
        for (int mk = 1; mk < 64; mk <<= 1) {
            a00p += __shfl_xor(a00p, mk, 64);
            a01p += __shfl_xor(a01p, mk, 64);
        }
        if (l == 0) { anode[2 * n] = a00p; anode[2 * n + 1] = a01p; }

        {
            float acc = 0.f;
#pragma unroll
            for (int j = 0; j < 21; j++) acc += sfa[j] * Mk[j * 64 + l];
            qkp[n * 64 + l] = acc;
        }
        return;
    }

    // ---------------- edge path: wave = 64 edges
    char* lds = lds_all[wv];
    int e0 = (blockIdx.x * 4 + wv) * 64;
    if (e0 + 64 > EF) e0 = EF - 64;

    if (mask[e0] < 0.5f) return;

    int s = src[e0 + l], d = dst[e0 + l];
    float2 xs = ((const float2*)x)[s], xd = ((const float2*)x)[d];
    float dx = xs.x - xd.x, dy = xs.y - xd.y;
    float r = sqrtf(fmaxf(dx * dx + dy * dy, 1e-12f));
    float da = angle[s] - angle[d];
    float sv, cv; sincosf(da, &sv, &cv);
    const float4* m4 = (const float4*)mol;
    float4 sa = m4[s * 4 + 0], sb = m4[s * 4 + 1], sc = m4[s * 4 + 2], sd = m4[s * 4 + 3];
    float4 ta = m4[d * 4 + 0], tb = m4[d * 4 + 1], tc = m4[d * 4 + 2], td = m4[d * 4 + 3];
    float f[22];
    f[0] = dx; f[1] = dy; f[2] = r; f[3] = sv; f[4] = cv;
    f[5]  = sa.x - ta.x; f[6]  = sa.y - ta.y; f[7]  = sa.z - ta.z; f[8]  = sa.w - ta.w;
    f[9]  = sb.x - tb.x; f[10] = sb.y - tb.y; f[11] = sb.z - tb.z; f[12] = sb.w - tb.w;
    f[13] = sc.x - tc.x; f[14] = sc.y - tc.y; f[15] = sc.z - tc.z; f[16] = sc.w - tc.w;
    f[17] = sd.x - td.x; f[18] = sd.y - td.y; f[19] = sd.z - td.z; f[20] = sd.w - td.w;
    f[21] = 1.f;
    unsigned p[16];
#pragma unroll
    for (int j = 0; j < 11; j++) p[j] = pk(f[2 * j], f[2 * j + 1]);
#pragma unroll
    for (int j = 11; j < 16; j++) p[j] = 0u;
#pragma unroll
    for (int g = 0; g < 4; g++) {
        int byte = l * 64 + ((g ^ (l & 3)) << 4);
        u4 w; w.x = p[4 * g]; w.y = p[4 * g + 1]; w.z = p[4 * g + 2]; w.w = p[4 * g + 3];
        *(u4*)(lds + byte) = w;
    }

    u4 B1[4];
#pragma unroll
    for (int n = 0; n < 4; n++) {
        int e = n * 16 + (l & 15);
        int byte = e * 64 + ((((l >> 4) & 3) ^ (e & 3)) << 4);
        B1[n] = *(const u4*)(lds + byte);
    }

    f4 acc[4][4];
#pragma unroll
    for (int m = 0; m < 4; m++)
#pragma unroll
        for (int n = 0; n < 4; n++) { acc[m][n].x = 0.f; acc[m][n].y = 0.f; acc[m][n].z = 0.f; acc[m][n].w = 0.f; }

    const unsigned short* W1u = (const unsigned short*)W1b;
    const unsigned short* W2u = (const unsigned short*)W2b;
    const unsigned short* W3u = (const unsigned short*)W3b;
#pragma unroll
    for (int m = 0; m < 4; m++) {
        u4 w = *(const u4*)(W1u + (m * 16 + (l & 15)) * 32 + (l >> 4) * 8);
#pragma unroll
        for (int n = 0; n < 4; n++) MFMA(acc[m][n], w, B1[n]);
    }
    write_tiles(lds, l, acc, nullptr);

    u4 B2[4][2];
#pragma unroll
    for (int n = 0; n < 4; n++)
#pragma unroll
        for (int ks = 0; ks < 2; ks++) {
            int e = n * 16 + (l & 15);
            int g = ks * 4 + (l >> 4);
            B2[n][ks] = *(const u4*)(lds + e * 128 + ((g ^ (e & 7)) << 4));
        }
#pragma unroll
    for (int m = 0; m < 4; m++)
#pragma unroll
        for (int n = 0; n < 4; n++) { acc[m][n].x = 0.f; acc[m][n].y = 0.f; acc[m][n].z = 0.f; acc[m][n].w = 0.f; }
#pragma unroll
    for (int m = 0; m < 4; m++)
#pragma unroll
        for (int ks = 0; ks < 2; ks++) {
            u4 w = *(const u4*)(W2u + (m * 16 + (l & 15)) * 64 + ks * 32 + (l >> 4) * 8);
#pragma unroll
            for (int n = 0; n < 4; n++) MFMA(acc[m][n], w, B2[n][ks]);
        }
    write_tiles(lds, l, acc, mb2);

#pragma unroll
    for (int n = 0; n < 4; n++)
#pragma unroll
        for (int ks = 0; ks < 2; ks++) {
            int e = n * 16 + (l & 15);
            int g = ks * 4 + (l >> 4);
            B2[n][ks] = *(const u4*)(lds + e * 128 + ((g ^ (e & 7)) << 4));
        }
#pragma unroll
    for (int m = 0; m < 4; m++)
#pragma unroll
        for (int n = 0; n < 4; n++) { acc[m][n].x = 0.f; acc[m][n].y = 0.f; acc[m][n].z = 0.f; acc[m][n].w = 0.f; }
#pragma unroll
    for (int m = 0; m < 4; m++)
#pragma unroll
        for (int ks = 0; ks < 2; ks++) {
            u4 w = *(const u4*)(W3u + (m * 16 + (l & 15)) * 64 + ks * 32 + (l >> 4) * 8);
#pragma unroll
            for (int n = 0; n < 4; n++) MFMA(acc[m][n], w, B2[n][ks]);
        }
    write_tiles(lds, l, acc, mb3);

    // coalesced readout: 16B per lane, 8 edges per iter
#pragma unroll
    for (int it = 0; it < 8; it++) {
        int e = it * 8 + (l >> 3);
        int g = l & 7;
        u4 vv = *(const u4*)(lds + e * 128 + ((g ^ (e & 7)) << 4));
        *(u4*)((unsigned short*)msg + (size_t)(e0 + e) * 64 + g * 8) = vv;
    }
}

// ---------------------------------------------------------------- attention aggregate (8 edge-groups of 8 lanes)
__global__ __launch_bounds__(256) void k_attn(
    const int* __restrict__ row_off, const int* __restrict__ src,
    const __hip_bfloat16* __restrict__ msg,
    const __hip_bfloat16* __restrict__ selffb, const float* __restrict__ qkp,
    const float* __restrict__ qwe, const float* __restrict__ anode,
    __hip_bfloat16* __restrict__ agg, float* __restrict__ invp)
{
    int tid = threadIdx.x, wid = tid >> 6, lane = tid & 63;
    int g = lane >> 3, c8 = lane & 7;
    int n = blockIdx.x * 4 + wid;

    const float* qrow = qwe + (size_t)n * 192;
    f4 qmA0 = *(const f4*)(qrow + 8 * c8);
    f4 qmA1 = *(const f4*)(qrow + 8 * c8 + 4);
    f4 qmB0 = *(const f4*)(qrow + 96 + 8 * c8);
    f4 qmB1 = *(const f4*)(qrow + 96 + 8 * c8 + 4);
    f4 qk0 = *(const f4*)(qkp + n * 64 + 4 * c8);
    f4 qk1 = *(const f4*)(qkp + n * 64 + 32 + 4 * c8);
    float2 av = *(const float2*)(anode + 2 * n);
    float a00 = av.x, a01 = av.y;

    const unsigned short* msgu = (const unsigned short*)msg;
    const unsigned short* sfu  = (const unsigned short*)selffb;
    f4 sfd = bf2f4(*(const ushort4*)(sfu + (size_t)n * 32 + 4 * c8));

    int r0 = row_off[n], r1 = row_off[n + 1];
    int nit = (r1 - r0 + 7) >> 3;

    f4 WmA0 = {0,0,0,0}, WmA1 = {0,0,0,0}, WmB0 = {0,0,0,0}, WmB1 = {0,0,0,0};
    f4 Ws0 = {0,0,0,0}, Ws1 = {0,0,0,0};
    float S0 = 0.f, S1 = 0.f;

#pragma unroll 2
    for (int it = 0; it < nit; it++) {
        int e = r0 + it * 8 + g;
        bool ok = (e < r1);
        int ec = ok ? e : r0;
        int s = src[ec];
        f4 sfv = bf2f4(*(const ushort4*)(sfu + (size_t)s * 32 + 4 * c8));
        u4 mr = *(const u4*)(msgu + (size_t)ec * 64 + 8 * c8);
        float c0 = __builtin_bit_cast(float, mr.x << 16);
        float c1 = __builtin_bit_cast(float, mr.x & 0xffff0000u);
        float c2 = __builtin_bit_cast(float, mr.y << 16);
        float c3 = __builtin_bit_cast(float, mr.y & 0xffff0000u);
        float c4 = __builtin_bit_cast(float, mr.z << 16);
        float c5 = __builtin_bit_cast(float, mr.z & 0xffff0000u);
        float c6 = __builtin_bit_cast(float, mr.w << 16);
        float c7 = __builtin_bit_cast(float, mr.w & 0xffff0000u);

        float t0 = qmA0.x * c0 + qmA0.y * c1 + qmA0.z * c2 + qmA0.w * c3
                 + qmA1.x * c4 + qmA1.y * c5 + qmA1.z * c6 + qmA1.w * c7
                 + dot4(sfv, qk0);
        float t1 = qmB0.x * c0 + qmB0.y * c1 + qmB0.z * c2 + qmB0.w * c3
                 + qmB1.x * c4 + qmB1.y * c5 + qmB1.z * c6 + qmB1.w * c7
                 + dot4(sfv, qk1);
#pragma unroll
        for (int mk = 1; mk < 8; mk <<= 1) {
            t0 += __shfl_xor(t0, mk, 64);
            t1 += __shfl_xor(t1, mk, 64);
        }
        float w0 = ok ? __expf((t0 + a00) * 0.125f) : 0.f;
        float w1 = ok ? __expf((t1 + a01) * 0.125f) : 0.f;
        S0 += w0; S1 += w1;
        WmA0.x += w0 * c0; WmA0.y += w0 * c1; WmA0.z += w0 * c2; WmA0.w += w0 * c3;
        WmA1.x += w0 * c4; WmA1.y += w0 * c5; WmA1.z += w0 * c6; WmA1.w += w0 * c7;
        WmB0.x += w1 * c0; WmB0.y += w1 * c1; WmB0.z += w1 * c2; WmB0.w += w1 * c3;
        WmB1.x += w1 * c4; WmB1.y += w1 * c5; WmB1.z += w1 * c6; WmB1.w += w1 * c7;
        Ws0.x += w0 * sfv.x; Ws0.y += w0 * sfv.y; Ws0.z += w0 * sfv.z; Ws0.w += w0 * sfv.w;
        Ws1.x += w1 * sfv.x; Ws1.y += w1 * sfv.y; Ws1.z += w1 * sfv.z; Ws1.w += w1 * sfv.w;
    }

#pragma unroll
    for (int mk = 8; mk <= 32; mk <<= 1) {
        WmA0.x += __shfl_xor(WmA0.x, mk, 64); WmA0.y += __shfl_xor(WmA0.y, mk, 64);
        WmA0.z += __shfl_xor(WmA0.z, mk, 64); WmA0.w += __shfl_xor(WmA0.w, mk, 64);
        WmA1.x += __shfl_xor(WmA1.x, mk, 64); WmA1.y += __shfl_xor(WmA1.y, mk, 64);
        WmA1.z += __shfl_xor(WmA1.z, mk, 64); WmA1.w += __shfl_xor(WmA1.w, mk, 64);
        WmB0.x += __shfl_xor(WmB0.x, mk, 64); WmB0.y += __shfl_xor(WmB0.y, mk, 64);
        WmB0.z += __shfl_xor(WmB0.z, mk, 64); WmB0.w += __shfl_xor(WmB0.w, mk, 64);
        WmB1.x += __shfl_xor(WmB1.x, mk, 64); WmB1.y += __shfl_xor(WmB1.y, mk, 64);
        WmB1.z += __shfl_xor(WmB1.z, mk, 64); WmB1.w += __shfl_xor(WmB1.w, mk, 64);
        Ws0.x += __shfl_xor(Ws0.x, mk, 64); Ws0.y += __shfl_xor(Ws0.y, mk, 64);
        Ws0.z += __shfl_xor(Ws0.z, mk, 64); Ws0.w += __shfl_xor(Ws0.w, mk, 64);
        Ws1.x += __shfl_xor(Ws1.x, mk, 64); Ws1.y += __shfl_xor(Ws1.y, mk, 64);
        Ws1.z += __shfl_xor(Ws1.z, mk, 64); Ws1.w += __shfl_xor(Ws1.w, mk, 64);
        S0 += __shfl_xor(S0, mk, 64); S1 += __shfl_xor(S1, mk, 64);
    }

    unsigned short* arow = (unsigned short*)agg + (size_t)n * 256;
    if (g == 0) {
        u4 w; w.x = pk(WmA0.x, WmA0.y); w.y = pk(WmA0.z, WmA0.w);
        w.z = pk(WmA1.x, WmA1.y); w.w = pk(WmA1.z, WmA1.w);
        *(u4*)(arow + 8 * c8) = w;
    } else if (g == 1) {
        u4 w; w.x = pk(WmB0.x, WmB0.y); w.y = pk(WmB0.z, WmB0.w);
        w.z = pk(WmB1.x, WmB1.y); w.w = pk(WmB1.z, WmB1.w);
        *(u4*)(arow + 128 + 8 * c8) = w;
    } else if (g == 2) {
        uint2 w; w.x = pk(Ws0.x, Ws0.y); w.y = pk(Ws0.z, Ws0.w);
        *(uint2*)(arow + 64 + 4 * c8) = w;
    } else if (g == 3) {
        uint2 w; w.x = pk(Ws1.x, Ws1.y); w.y = pk(Ws1.z, Ws1.w);
        *(uint2*)(arow + 128 + 64 + 4 * c8) = w;
    } else if (g == 4) {
        uint2 w; w.x = pk(S0 * sfd.x, S0 * sfd.y); w.y = pk(S0 * sfd.z, S0 * sfd.w);
        *(uint2*)(arow + 96 + 4 * c8) = w;
    } else if (g == 5) {
        uint2 w; w.x = pk(S1 * sfd.x, S1 * sfd.y); w.y = pk(S1 * sfd.z, S1 * sfd.w);
        *(uint2*)(arow + 128 + 96 + 4 * c8) = w;
    } else if (g == 6 && c8 == 0) {
        invp[2 * n]     = 1.f / (S0 + 1e-16f);
        invp[2 * n + 1] = 1.f / (S1 + 1e-16f);
    }
}

// ---------------------------------------------------------------- fused attn-epilogue + final MLP (1 wave = 64 nodes)
__global__ __launch_bounds__(64) void k_final2(
    const __hip_bfloat16* __restrict__ agg, const float* __restrict__ invp,
    const float* __restrict__ skipf, const __hip_bfloat16* __restrict__ WcA,
    const __hip_bfloat16* __restrict__ H1b, const __hip_bfloat16* __restrict__ H2b,
    const __hip_bfloat16* __restrict__ H3b,
    const float* __restrict__ hb1, const float* __restrict__ hb2, const float* __restrict__ hb3,
    float* __restrict__ out)
{
    __shared__ char lds[64 * 128];
    int l = threadIdx.x;
    int n0 = blockIdx.x * 64;

    const unsigned short* aggU = (const unsigned short*)agg;
    const unsigned short* WcU = (const unsigned short*)WcA;
    const unsigned short* H1u = (const unsigned short*)H1b;
    const unsigned short* H2u = (const unsigned short*)H2b;
    const unsigned short* H3u = (const unsigned short*)H3b;

    int nodes[4];
    float inv0[4], inv1[4];
#pragma unroll
    for (int n4 = 0; n4 < 4; n4++) {
        int node = n0 + n4 * 16 + (l & 15); if (node >= NN) node = NN - 1;
        nodes[n4] = node;
        float2 iv = *(const float2*)(invp + 2 * node);
        inv0[n4] = iv.x; inv1[n4] = iv.y;
    }

    f4 osum[4][4];
#pragma unroll
    for (int m = 0; m < 4; m++)
#pragma unroll
        for (int n4 = 0; n4 < 4; n4++) { osum[m][n4].x = 0.f; osum[m][n4].y = 0.f; osum[m][n4].z = 0.f; osum[m][n4].w = 0.f; }

#pragma unroll
    for (int h = 0; h < 2; h++) {
        f4 acc[4][4];
#pragma unroll
        for (int m = 0; m < 4; m++)
#pragma unroll
            for (int n4 = 0; n4 < 4; n4++) { acc[m][n4].x = 0.f; acc[m][n4].y = 0.f; acc[m][n4].z = 0.f; acc[m][n4].w = 0.f; }
#pragma unroll
        for (int ks = 0; ks < 4; ks++) {
            u4 A[4];
#pragma unroll
            for (int m = 0; m < 4; m++)
                A[m] = *(const u4*)(WcU + h * 8192 + (m * 16 + (l & 15)) * 128 + ks * 32 + (l >> 4) * 8);
#pragma unroll
            for (int n4 = 0; n4 < 4; n4++) {
                u4 B = *(const u4*)(aggU + (size_t)nodes[n4] * 256 + h * 128 + ks * 32 + (l >> 4) * 8);
#pragma unroll
                for (int m = 0; m < 4; m++) MFMA(acc[m][n4], A[m], B);
            }
        }
        const float* iv = h ? inv1 : inv0;
#pragma unroll
        for (int m = 0; m < 4; m++)
#pragma unroll
            for (int n4 = 0; n4 < 4; n4++) {
                float s = 0.5f * iv[n4];
                osum[m][n4].x += s * acc[m][n4].x; osum[m][n4].y += s * acc[m][n4].y;
                osum[m][n4].z += s * acc[m][n4].z; osum[m][n4].w += s * acc[m][n4].w;
            }
    }

#pragma unroll
    for (int m = 0; m < 4; m++) {
#pragma unroll
        for (int n4 = 0; n4 < 4; n4++) {
            int ch0 = m * 16 + ((l >> 4) << 2);
            float4 sk = *(const float4*)(skipf + (size_t)nodes[n4] * 64 + ch0);
            f4 v = osum[m][n4];
            float v0 = v.x + sk.x, v1 = v.y + sk.y, v2 = v.z + sk.z, v3 = v.w + sk.w;
            int e = n4 * 16 + (l & 15);
            int byte = e * 128 + ((((ch0 >> 3) ^ (e & 7))) << 4) + (ch0 & 7) * 2;
            uint2 w; w.x = pk(v0, v1); w.y = pk(v2, v3);
            *(uint2*)(lds + byte) = w;
        }
    }
    __syncthreads();

    u4 B[4][2];
    f4 acc[4][4];

    // ---- stage 1
#pragma unroll
    for (int n = 0; n < 4; n++)
#pragma unroll
        for (int ks = 0; ks < 2; ks++) {
            int e = n * 16 + (l & 15);
            int g = ks * 4 + (l >> 4);
            B[n][ks] = *(const u4*)(lds + e * 128 + ((g ^ (e & 7)) << 4));
        }
    __syncthreads();
#pragma unroll
    for (int m = 0; m < 4; m++)
#pragma unroll
        for (int n = 0; n < 4; n++) { acc[m][n].x = 0.f; acc[m][n].y = 0.f; acc[m][n].z = 0.f; acc[m][n].w = 0.f; }
#pragma unroll
    for (int m = 0; m < 4; m++)
#pragma unroll
        for (int ks = 0; ks < 2; ks++) {
            u4 w = *(const u4*)(H1u + (m * 16 + (l & 15)) * 64 + ks * 32 + (l >> 4) * 8);
#pragma unroll
            for (int n = 0; n < 4; n++) MFMA(acc[m][n], w, B[n][ks]);
        }
    write_tiles(lds, l, acc, hb1);
    __syncthreads();

    // ---- stage 2
#pragma unroll
    for (int n = 0; n < 4; n++)
#pragma unroll
        for (int ks = 0; ks < 2; ks++) {
            int e = n * 16 + (l & 15);
            int g = ks * 4 + (l >> 4);
            B[n][ks] = *(const u4*)(lds + e * 128 + ((g ^ (e & 7)) << 4));
        }
    __syncthreads();
#pragma unroll
    for (int m = 0; m < 4; m++)
#pragma unroll
        for (int n = 0; n < 4; n++) { acc[m][n].x = 0.f; acc[m][n].y = 0.f; acc[m][n].z = 0.f; acc[m][n].w = 0.f; }
#pragma unroll
    for (int m = 0; m < 4; m++)
#pragma unroll
        for (int ks = 0; ks < 2; ks++) {
            u4 w = *(const u4*)(H2u + (m * 16 + (l & 15)) * 64 + ks * 32 + (l >> 4) * 8);
#pragma unroll
            for (int n = 0; n < 4; n++) MFMA(acc[m][n], w, B[n][ks]);
        }
    write_tiles(lds, l, acc, hb2);
    __syncthreads();

    // ---- stage 3: 64 -> 20
#pragma unroll
    for (int n = 0; n < 4; n++)
#pragma unroll
        for (int ks = 0; ks < 2; ks++) {
            int e = n * 16 + (l & 15);
            int g = ks * 4 + (l >> 4);
            B[n][ks] = *(const u4*)(lds + e * 128 + ((g ^ (e & 7)) << 4));
        }

    f4 acc3[2][4];
#pragma unroll
    for (int m = 0; m < 2; m++)
#pragma unroll
        for (int n = 0; n < 4; n++) { acc3[m][n].x = 0.f; acc3[m][n].y = 0.f; acc3[m][n].z = 0.f; acc3[m][n].w = 0.f; }
#pragma unroll
    for (int m = 0; m < 2; m++)
#pragma unroll
        for (int ks = 0; ks < 2; ks++) {
            u4 w = *(const u4*)(H3u + (m * 16 + (l & 15)) * 64 + ks * 32 + (l >> 4) * 8);
#pragma unroll
            for (int n = 0; n < 4; n++) MFMA(acc3[m][n], w, B[n][ks]);
        }

#pragma unroll
    for (int m = 0; m < 2; m++) {
#pragma unroll
        for (int j = 0; j < 4; j++) {
            int ch = m * 16 + (l >> 4) * 4 + j;
            if (ch < 20) {
                float b = hb3[ch];
#pragma unroll
                for (int nt = 0; nt < 4; nt++) {
                    int node = n0 + nt * 16 + (l & 15);
                    if (node < NN) {
                        float v = acc3[m][nt][j] + b;
                        if (ch < 2)       out[node * 2 + ch] = v;
                        else if (ch == 2) out[2 * NN + node] = v;
                        else if (ch < 19) out[3 * NN + node * 16 + (ch - 3)] = v;
                        else              out[19 * NN + node] = v;
                    }
                }
            }
        }
    }
}

// ---------------------------------------------------------------- launch
extern "C" void kernel_launch(void* const* d_in, const int* in_sizes, int n_in,
                              void* d_out, int out_size, void* d_ws, size_t ws_size,
                              hipStream_t stream)
{
    const float* x      = (const float*)d_in[0];
    const float* angle  = (const float*)d_in[1];
    const float* mol    = (const float*)d_in[2];
    const float* gen    = (const float*)d_in[3];
    const int*   src    = (const int*)d_in[4];
    const int*   dst    = (const int*)d_in[5];
    const float* mask   = (const float*)d_in[6];
    const float* mw1    = (const float*)d_in[7];
    const float* mb1    = (const float*)d_in[8];
    const float* mw2    = (const float*)d_in[9];
    const float* mb2    = (const float*)d_in[10];
    const float* mw3    = (const float*)d_in[11];
    const float* mb3    = (const float*)d_in[12];
    const float* wq     = (const float*)d_in[13];
    const float* bq     = (const float*)d_in[14];
    const float* wk     = (const float*)d_in[15];
    const float* bk     = (const float*)d_in[16];
    const float* wv     = (const float*)d_in[17];
    const float* bv     = (const float*)d_in[18];
    const float* we     = (const float*)d_in[19];
    const float* wskip  = (const float*)d_in[20];
    const float* bskip  = (const float*)d_in[21];
    const float* hw1    = (const float*)d_in[22];
    const float* hb1    = (const float*)d_in[23];
    const float* hw2    = (const float*)d_in[24];
    const float* hb2    = (const float*)d_in[25];
    const float* hw3    = (const float*)d_in[26];
    const float* hb3    = (const float*)d_in[27];
    float* out = (float*)d_out;

    char* p = (char*)d_ws;
    auto alloc = [&](size_t bytes) -> void* {
        void* r = (void*)p;
        p += (bytes + 255) & ~(size_t)255;
        return r;
    };
    int*   row_off = (int*)alloc((NN + 1) * 4);
    __hip_bfloat16* selffb = (__hip_bfloat16*)alloc((size_t)NN * 32 * 2);
    float* qkp     = (float*)alloc((size_t)NN * 64 * 4);
    float* skipf   = (float*)alloc((size_t)NN * 64 * 4);
    float* qwe     = (float*)alloc((size_t)NN * 192 * 4);
    float* anode   = (float*)alloc((size_t)NN * 2 * 4);
    __hip_bfloat16* agg = (__hip_bfloat16*)alloc((size_t)NN * 256 * 2);
    float* invp    = (float*)alloc((size_t)NN * 2 * 4);
    __hip_bfloat16* W1b = (__hip_bfloat16*)alloc(2048 * 2);
    __hip_bfloat16* W2b = (__hip_bfloat16*)alloc(4096 * 2);
    __hip_bfloat16* W3b = (__hip_bfloat16*)alloc(4096 * 2);
    __hip_bfloat16* H1b = (__hip_bfloat16*)alloc(4096 * 2);
    __hip_bfloat16* H2b = (__hip_bfloat16*)alloc(4096 * 2);
    __hip_bfloat16* H3b = (__hip_bfloat16*)alloc(2048 * 2);
    __hip_bfloat16* WcA = (__hip_bfloat16*)alloc(16384 * 2);
    float* Mwe     = (float*)alloc(4032 * 4);
    float* Mk      = (float*)alloc(1344 * 4);
    __hip_bfloat16* msg = (__hip_bfloat16*)alloc((size_t)EF * 64 * 2);

    k_prep<<<165, 256, 0, stream>>>(mw1, mb1, mw2, mw3, hw1, hw2, hw3, we, wk, bk, wv, bv,
                                    wq, bq, W1b, W2b, W3b, H1b, H2b, H3b, WcA, Mwe, Mk);
    k_csr<<<(NN + 256) / 256, 256, 0, stream>>>(dst, mask, row_off);
    k_edge_node<<<EB + NN / 4, 256, 0, stream>>>(x, angle, mol, gen, src, dst, mask, row_off,
                                                 W1b, W2b, W3b, mb2, mb3,
                                                 wskip, bskip, Mwe, Mk,
                                                 msg, selffb, skipf, qwe, qkp, anode);
    k_attn<<<NN / 4, 256, 0, stream>>>(row_off, src, msg, selffb, qkp,
                                       qwe, anode, agg, invp);
    k_final2<<<(NN + 63) / 64, 64, 0, stream>>>(agg, invp, skipf, WcA,
                                                H1b, H2b, H3b, hb1, hb2, hb3, out);
}